// Round 7
// baseline (268.375 us; speedup 1.0000x reference)
//
#include <hip/hip_runtime.h>
#include <stdint.h>

typedef unsigned short ushort_t;
typedef __bf16 bf16x8 __attribute__((ext_vector_type(8)));
typedef float  f32x4  __attribute__((ext_vector_type(4)));

#define DEV static __device__ __forceinline__

// fp32 -> bf16 round-to-nearest-even
DEV ushort_t f2bf(float f){
  union { float f; unsigned u; } x; x.f = f;
  unsigned u = x.u;
  return (ushort_t)((u + 0x7fffu + ((u >> 16) & 1u)) >> 16);
}

// Boustrophedon map for S=8192 (g=91): involution, maps permuted<->original.
DEV int hmap(int p){
  int r = p / 91;
  int c = p - r * 91;
  return (r & 1) ? (r * 91 + 90 - c) : p;
}

// A-row gather (runtime): 0 identity; 1 = Q permuted order; 2 = compacted dilated KV.
DEV int arow_rt(int r, int gather){
  if (gather == 0) return r;
  if (gather == 1){ int b = r >> 13, p = r & 8191; return b * 8192 + hmap(p); }
  int b = r >> 12, rem = r & 4095, seg = rem >> 6, j = rem & 63;
  return b * 8192 + hmap(seg * 128 + 2 * j);
}

// async global->LDS 16B per lane (LDS dest must be wave-uniform base + lane*16)
DEV void async16(const void* g, void* l){
  __builtin_amdgcn_global_load_lds(
      (const __attribute__((address_space(1))) unsigned*)g,
      (__attribute__((address_space(3))) unsigned*)l, 16, 0, 0);
}

// swizzled LDS address for 64-elem bf16 rows staged by async16 with
// pre-swizzled global chunk: elem (r,c) lives at r*64 + ((c>>3)^(r&7))*8 + (c&7)
DEV int sw64(int r, int c){
  return r * 64 + (((c >> 3) ^ (r & 7)) << 3) + (c & 7);
}

// ---------------- fused prep: cast x + transpose both weights ----------------
// blocks 0..2047: cast x (fp32->bf16, grid-stride over float4)
// blocks 2048..2815: transpose Wqkv [1024][3072] -> WqT [3072][1024]
// blocks 2816..3071: transpose Wout [1024][1024] -> WoT [1024][1024]
__global__ __launch_bounds__(256) void prep_kernel(const float* __restrict__ x,
                                                   const float* __restrict__ Wqkv,
                                                   const float* __restrict__ Wout,
                                                   ushort_t* __restrict__ xb,
                                                   ushort_t* __restrict__ WqT,
                                                   ushort_t* __restrict__ WoT){
  __shared__ ushort_t t[64 * 66];   // pad 66: conflict-free column reads
  int id = blockIdx.x, tid = threadIdx.x;
  if (id < 2048){
    const int n4 = (16384 * 1024) / 4;
    int stride = 2048 * 256;
    for (int i = id * 256 + tid; i < n4; i += stride){
      float4 v = ((const float4*)x)[i];
      ushort4 o;
      o.x = f2bf(v.x); o.y = f2bf(v.y); o.z = f2bf(v.z); o.w = f2bf(v.w);
      ((ushort4*)xb)[i] = o;
    }
    return;
  }
  const float* W; ushort_t* WT; int rows, cols, bx, by;
  if (id < 2816){ int q = id - 2048; W = Wqkv; WT = WqT; rows = 1024; cols = 3072; bx = q % 48; by = q / 48; }
  else          { int q = id - 2816; W = Wout; WT = WoT; rows = 1024; cols = 1024; bx = q % 16; by = q / 16; }
  int c0 = bx * 64, r0 = by * 64;
  int cl = tid & 63, rb = tid >> 6;
  for (int i = 0; i < 16; ++i){
    int r = rb + i * 4;
    t[r * 66 + cl] = f2bf(W[(size_t)(r0 + r) * cols + c0 + cl]);
  }
  __syncthreads();
  int rr = tid & 63, cb = tid >> 6;
  for (int i = 0; i < 16; ++i){
    int cc = cb + i * 4;
    WT[(size_t)(c0 + cc) * rows + r0 + rr] = t[rr * 66 + cc];
  }
}

// ================= 256x256 GEMM body (R4-frozen K-loop) =================
// C[M][N] = A[gather(M)][K] * BT[N][K]^T. BM=BN=256, BK=64, 512 thr (8 waves,
// 2Mx4N, wave tile 128x64). LDS: 4 objects As0/As1/Bs0/Bs1, 128 KiB, 1 blk/CU.
// K-loop = family optimum over 7 measured variants (44.5-48.5us, ~27% MfmaUtil
// = the plain-HIP 2-barrier structural ceiling per learn_hip m230/m233; at
// K=1024 the 8-phase upside is only ~10% (m248v2) and our port of it nulled).
//   STAGE(t+1 -> other buf); vmcnt(8); barrier; COMPUTE(t); barrier.
// Epilogue (R6 post-mortem): direct fp32 16x16 stores are 64B half-lines ->
// 2x WRITE_SIZE on C (measured ~128MB for a 64MB output). BOTH paths now
// re-tile per-wave through LDS with stride 68 (272B: 16B-aligned float4 reads
// -> real ds_read_b128, R6's stride-65 was misaligned -> its 1.05M conflicts)
// then store full 128B lines (ushort4 x16 lanes / float4 x16 lanes).

#define BARRIER() asm volatile("s_barrier" ::: "memory")
#define VMCNT8()  asm volatile("s_waitcnt vmcnt(8)" ::: "memory")
#define VMCNT0()  asm volatile("s_waitcnt vmcnt(0)" ::: "memory")

#define STAGE_A_TO(DST, T1)                                                    \
  {                                                                            \
    _Pragma("unroll") for (int i = 0; i < 4; ++i)                              \
      async16(&A[asrcR[i] + (size_t)(T1) * 64], &DST[i * 4096 + tid * 8]);     \
  }

#define STAGE_B_TO(DST, T1)                                                    \
  {                                                                            \
    _Pragma("unroll") for (int i = 0; i < 4; ++i)                              \
      async16(&BT[bsrcR[i] + (size_t)(T1) * 64], &DST[i * 4096 + tid * 8]);    \
  }

#define COMPUTE(ABUF, BBUF)                                                    \
  {                                                                            \
    bf16x8 bv[4][2];                                                           \
    _Pragma("unroll") for (int ni = 0; ni < 4; ++ni)                           \
      _Pragma("unroll") for (int kk = 0; kk < 2; ++kk)                         \
        bv[ni][kk] = *(const bf16x8*)&BBUF[(wn * 64 + ni * 16 + md) * 64 + axor[kk]]; \
    _Pragma("unroll") for (int kk = 0; kk < 2; ++kk)                           \
      _Pragma("unroll") for (int mi = 0; mi < 8; ++mi){                        \
        bf16x8 af = *(const bf16x8*)&ABUF[(wm * 128 + mi * 16 + md) * 64 + axor[kk]]; \
        _Pragma("unroll") for (int ni = 0; ni < 4; ++ni)                       \
          acc[mi][ni] = __builtin_amdgcn_mfma_f32_16x16x32_bf16(               \
              af, bv[ni][kk], acc[mi][ni], 0, 0, 0);                           \
      }                                                                        \
  }

#define TILE_STEP(CUR, NXT, TSTAGE)                                            \
  {                                                                            \
    if ((TSTAGE) < NT){                                                        \
      STAGE_A_TO(As##NXT, TSTAGE); STAGE_B_TO(Bs##NXT, TSTAGE);                \
      VMCNT8();                                                                \
    } else { VMCNT0(); }                                                       \
    BARRIER();                                                                 \
    COMPUTE(As##CUR, Bs##CUR);                                                 \
    BARRIER();                                                                 \
  }

template<int OUT_BF16>
DEV void gemm_body(const ushort_t* __restrict__ A, const ushort_t* __restrict__ BT,
                   void* __restrict__ Cout, int N, int K, int gather, int m0, int n0,
                   ushort_t* As0, ushort_t* As1, ushort_t* Bs0, ushort_t* Bs1){
  const int NT = K >> 6;                           // K-tiles (=16, even)
  int tid = threadIdx.x;
  int lane = tid & 63, w = tid >> 6;
  int md = lane & 15, qd = lane >> 4;
  int wm = w >> 2, wn = w & 3;

  // staging: thread covers LDS rows i*64 + (tid>>3), slot tid&7; global chunk
  // g0 = slot ^ (row&7)  ((64*i)&7==0 so g0 is i-independent)
  int rbase = tid >> 3;
  int g0 = ((tid & 7) ^ (rbase & 7)) * 8;          // elems
  size_t asrcR[4], bsrcR[4];
  #pragma unroll
  for (int i = 0; i < 4; ++i){
    asrcR[i] = (size_t)arow_rt(m0 + i * 64 + rbase, gather) * K + g0;
    bsrcR[i] = (size_t)(n0 + i * 64 + rbase) * K + g0;
  }

  // fragment offsets: frag row = (multiple of 8) + md -> row&7 == md&7
  int axor[2] = { (qd ^ (md & 7)) * 8, ((4 + qd) ^ (md & 7)) * 8 };

  f32x4 acc[8][4];
  #pragma unroll
  for (int a = 0; a < 8; ++a)
    #pragma unroll
    for (int b = 0; b < 4; ++b)
      #pragma unroll
      for (int e = 0; e < 4; ++e) acc[a][b][e] = 0.f;

  // prologue: tile 0 into buffers 0 (cold-start latency exposed once)
  STAGE_A_TO(As0, 0);
  STAGE_B_TO(Bs0, 0);
  VMCNT0(); BARRIER();

  for (int t = 0; t < NT; t += 2){
    TILE_STEP(0, 1, t + 1);
    TILE_STEP(1, 0, t + 2);
  }

  // ---- epilogue: 16x16 C/D layout col=lane&15, row=(lane>>4)*4+reg ----
  // Per-wave LDS re-tile (wave-private -> no barrier; LDS free after the final
  // barrier). Stride 68 floats = 272B: float4 reads 16B-aligned, banks 2-way
  // (free, m136). Full-line global stores.
  float* wbuf = (float*)((w < 4) ? (void*)As0 : (void*)As1) + (w & 3) * 1088;
  int r16 = lane >> 4, c16 = lane & 15;
  #pragma unroll
  for (int mi = 0; mi < 8; ++mi){
    #pragma unroll
    for (int ni = 0; ni < 4; ++ni)
      #pragma unroll
      for (int reg = 0; reg < 4; ++reg)
        wbuf[(qd * 4 + reg) * 68 + ni * 16 + md] = acc[mi][ni][reg];
    // same-wave ds_write -> ds_read ordering is maintained by the LDS unit
    #pragma unroll
    for (int rr = 0; rr < 4; ++rr){
      int row = rr * 4 + r16;
      float4 v = *(const float4*)&wbuf[row * 68 + c16 * 4];
      int grow = m0 + wm * 128 + mi * 16 + row;
      int gcol = n0 + wn * 64 + c16 * 4;
      if (OUT_BF16){
        ushort4 ob;
        ob.x = f2bf(v.x); ob.y = f2bf(v.y); ob.z = f2bf(v.z); ob.w = f2bf(v.w);
        *(ushort4*)&((ushort_t*)Cout)[(size_t)grow * N + gcol] = ob;   // 16 lanes x 8B = 128B line
      } else {
        *(float4*)&((float*)Cout)[(size_t)grow * N + gcol] = v;        // 16 lanes x 16B = 2 full lines
      }
    }
  }
}

// -------- fused Q + KV projection: 512 blocks, block-routed --------
__global__ __launch_bounds__(512, 2) void gemm_qkv(const ushort_t* __restrict__ xb,
                                                   const ushort_t* __restrict__ WqT,
                                                   ushort_t* __restrict__ Qbuf,
                                                   ushort_t* __restrict__ KVbuf){
  __shared__ __align__(16) ushort_t As0[16384];
  __shared__ __align__(16) ushort_t As1[16384];
  __shared__ __align__(16) ushort_t Bs0[16384];
  __shared__ __align__(16) ushort_t Bs1[16384];
  int id = blockIdx.x;
  const ushort_t* BT; ushort_t* C; int N, gather, m0, n0;
  if (id < 256){
    int o = id;                       // n-major, mtc=64
    m0 = (o & 63) << 8; n0 = (o >> 6) << 8;
    BT = WqT; C = Qbuf; N = 1024; gather = 1;
  } else {
    int o = id - 256;                 // n-major, mtc=32
    m0 = (o & 31) << 8; n0 = (o >> 5) << 8;
    BT = WqT + (size_t)1024 * 1024; C = KVbuf; N = 2048; gather = 2;
  }
  gemm_body<1>(xb, BT, C, N, 1024, gather, m0, n0, As0, As1, Bs0, Bs1);
}

// -------- output projection: fp32 out, identity gather --------
__global__ __launch_bounds__(512, 2) void gemm_out(const ushort_t* __restrict__ aoutb,
                                                   const ushort_t* __restrict__ WoT,
                                                   float* __restrict__ out){
  __shared__ __align__(16) ushort_t As0[16384];
  __shared__ __align__(16) ushort_t As1[16384];
  __shared__ __align__(16) ushort_t Bs0[16384];
  __shared__ __align__(16) ushort_t Bs1[16384];
  int o = blockIdx.x;                 // n-major, mtc=64
  int m0 = (o & 63) << 8, n0 = (o >> 6) << 8;
  gemm_body<0>(aoutb, WoT, out, 1024, 1024, 0, m0, n0, As0, As1, Bs0, Bs1);
}

// ---------------- fused segment attention ----------------
// grid (nseg=64, H=16, B=2), block 256 (4 waves).
// Qb:  [B*8192][1024] bf16, rows already in PERMUTED order (gather=1).
// KV:  [B*4096][2048] bf16, compacted dilated rows; cols 0..1023 = K, 1024.. = V.
// R7: Q and K staged via global_load_lds (linear LDS dest, pre-swizzled global
// chunk — the GEMM-verified pattern) into 64-wide swizzled layouts; removes
// the VGPR round-trip and shrinks LDS 36.9->33 KB. All swizzled accesses go
// through sw64(). V keeps the reg-transpose path into stride-72 Vt (b128
// alignment requires 144B rows there). P and O alias Qs (wave-private rows)
// using the same sw64 layout. Numerics identical to R6.
__global__ __launch_bounds__(256) void attn_kernel(const ushort_t* __restrict__ Qb,
                                                   const ushort_t* __restrict__ KV,
                                                   ushort_t* __restrict__ aout){
  __shared__ __align__(16) ushort_t Qs[128 * 64];  // Q, then P, then O (sw64 layout)
  __shared__ __align__(16) ushort_t Ks[64 * 64];   // K (sw64 layout)
  __shared__ ushort_t Vt[64 * 72];                 // V^T, k-chunk swizzled (R6 layout)
  int tid  = threadIdx.x;
  int lane = tid & 63, w = tid >> 6;
  int qd = lane >> 4, md = lane & 15;
  int seg = blockIdx.x, h = blockIdx.y, b = blockIdx.z;
  int p0 = seg * 128;

  // Q: 128 rows x 128B, DMA; thread covers (r = q>>3, ch = q&7), source chunk
  // pre-swizzled ch^(r&7), LDS dest linear q*16B (wave-uniform base + lane*16)
  #pragma unroll
  for (int it = 0; it < 4; ++it){
    int q = it * 256 + tid, r = q >> 3, ch = q & 7;
    async16(&Qb[(size_t)(b * 8192 + p0 + r) * 1024 + h * 64 + ((ch ^ (r & 7)) << 3)],
            &Qs[q * 8]);
  }
  // K: 64 rows, same pattern
  #pragma unroll
  for (int it = 0; it < 2; ++it){
    int q = it * 256 + tid, r = q >> 3, ch = q & 7;
    async16(&KV[(size_t)(b * 4096 + seg * 64 + r) * 2048 + h * 64 + ((ch ^ (r & 7)) << 3)],
            &Ks[q * 8]);
  }
  // V (cols 1024..2047): reg path, transposed store with swizzled k-chunk:
  // element V[k=r][d=ch*8+e] -> Vt[d*72 + ((r>>3)^ch)*8 + (r&7)]
  #pragma unroll
  for (int it = 0; it < 2; ++it){
    int q = it * 256 + tid, r = q >> 3, ch = q & 7;
    union { uint4 v; ushort_t u[8]; } d;
    d.v = *(const uint4*)&KV[(size_t)(b * 4096 + seg * 64 + r) * 2048 + 1024 + h * 64 + ch * 8];
    int kslot = ((r >> 3) ^ ch) * 8 + (r & 7);
    #pragma unroll
    for (int e = 0; e < 8; ++e) Vt[(ch * 8 + e) * 72 + kslot] = d.u[e];
  }
  __syncthreads();   // compiler drains vmcnt (DMAs) + lgkm (Vt writes)

  // scores: wave w owns q-rows [32w, 32w+32): 2 row-tiles x 4 col-tiles
  f32x4 z = {0.f, 0.f, 0.f, 0.f};
  f32x4 sc[2][4];
  for (int mi = 0; mi < 2; ++mi) for (int ni = 0; ni < 4; ++ni) sc[mi][ni] = z;
  for (int kc = 0; kc < 2; ++kc){
    bf16x8 aq[2], bk[4];
    for (int mi = 0; mi < 2; ++mi)
      aq[mi] = *(const bf16x8*)&Qs[sw64(w * 32 + mi * 16 + md, kc * 32 + qd * 8)];
    for (int ni = 0; ni < 4; ++ni)
      bk[ni] = *(const bf16x8*)&Ks[sw64(ni * 16 + md, kc * 32 + qd * 8)];
    for (int mi = 0; mi < 2; ++mi)
      for (int ni = 0; ni < 4; ++ni)
        sc[mi][ni] = __builtin_amdgcn_mfma_f32_16x16x32_bf16(aq[mi], bk[ni], sc[mi][ni], 0, 0, 0);
  }

  // softmax over 64 keys; scale 1/sqrt(64)=0.125. Row r lives in 16 lanes
  // (same quad) x 4 col-tiles -> in-register + shfl_xor(1,2,4,8) reduction.
  const float scale = 0.125f;
  ushort_t* Ps = Qs;  // alias: wave only touches its own 32 rows
  for (int mi = 0; mi < 2; ++mi){
    for (int i = 0; i < 4; ++i){
      float mx = sc[mi][0][i];
      for (int ni = 1; ni < 4; ++ni) mx = fmaxf(mx, sc[mi][ni][i]);
      for (int d = 1; d < 16; d <<= 1) mx = fmaxf(mx, __shfl_xor(mx, d));
      float e[4], sum = 0.f;
      for (int ni = 0; ni < 4; ++ni){ e[ni] = __expf((sc[mi][ni][i] - mx) * scale); sum += e[ni]; }
      for (int d = 1; d < 16; d <<= 1) sum += __shfl_xor(sum, d);
      float inv = 1.0f / sum;
      int r = w * 32 + mi * 16 + qd * 4 + i;
      for (int ni = 0; ni < 4; ++ni)
        Ps[sw64(r, ni * 16 + md)] = f2bf(e[ni] * inv);
    }
  }

  // O = P @ V : A = P (rows w*32..+31, sw64), B = Vt[d][k] (k-chunk swizzled)
  f32x4 oc[2][4];
  for (int mi = 0; mi < 2; ++mi) for (int ni = 0; ni < 4; ++ni) oc[mi][ni] = z;
  for (int kc = 0; kc < 2; ++kc){
    bf16x8 ap[2], bv[4];
    for (int mi = 0; mi < 2; ++mi)
      ap[mi] = *(const bf16x8*)&Ps[sw64(w * 32 + mi * 16 + md, kc * 32 + qd * 8)];
    for (int ni = 0; ni < 4; ++ni){
      int dd = ni * 16 + md;
      int vchunk = ((kc * 4 + qd) ^ ((dd >> 3) & 7)) & 7;
      bv[ni] = *(const bf16x8*)&Vt[dd * 72 + vchunk * 8];
    }
    for (int mi = 0; mi < 2; ++mi)
      for (int ni = 0; ni < 4; ++ni)
        oc[mi][ni] = __builtin_amdgcn_mfma_f32_16x16x32_bf16(ap[mi], bv[ni], oc[mi][ni], 0, 0, 0);
  }

  // O back into wave-private rows of Qs (sw64), then one barrier and
  // fully-coalesced 16B stores: row s=hmap(p0+r), 128B/row.
  for (int mi = 0; mi < 2; ++mi){
    for (int i = 0; i < 4; ++i){
      int rl = w * 32 + mi * 16 + qd * 4 + i;
      for (int ni = 0; ni < 4; ++ni)
        Ps[sw64(rl, ni * 16 + md)] = f2bf(oc[mi][ni][i]);
    }
  }
  __syncthreads();
  for (int it = 0; it < 4; ++it){
    int q = it * 256 + tid;
    int r = q >> 3, ch = q & 7;
    int s = hmap(p0 + r);
    *(uint4*)&aout[(size_t)(b * 8192 + s) * 1024 + h * 64 + ch * 8] =
        *(const uint4*)&Qs[sw64(r, ch * 8)];
  }
}

extern "C" void kernel_launch(void* const* d_in, const int* in_sizes, int n_in,
                              void* d_out, int out_size, void* d_ws, size_t ws_size,
                              hipStream_t stream){
  const float* x    = (const float*)d_in[0];   // [2,8192,1024]
  const float* Wqkv = (const float*)d_in[1];   // [1024,3072]
  const float* Wout = (const float*)d_in[2];   // [1024,1024]
  float* out = (float*)d_out;                  // [2,8192,1024]

  // ws layout (bytes): xb 32M | WqT 6M | WoT 2M | Qbuf 32M | KVbuf 32M | aout 32M = 136 MB
  char* ws = (char*)d_ws;
  ushort_t* xb    = (ushort_t*)(ws);
  ushort_t* WqT   = (ushort_t*)(ws + 33554432);
  ushort_t* WoT   = (ushort_t*)(ws + 39845888);
  ushort_t* Qbuf  = (ushort_t*)(ws + 41943040);
  ushort_t* KVbuf = (ushort_t*)(ws + 75497472);
  ushort_t* aoutb = (ushort_t*)(ws + 109051904);

  prep_kernel<<<3072, 256, 0, stream>>>(x, Wqkv, Wout, xb, WqT, WoT);
  gemm_qkv<<<512, 512, 0, stream>>>(xb, WqT, Qbuf, KVbuf);
  attn_kernel<<<dim3(64, 16, 2), 256, 0, stream>>>(Qbuf, KVbuf, aoutb);
  gemm_out<<<256, 512, 0, stream>>>(aoutb, WoT, out);
}

// Round 8
// 260.007 us; speedup vs baseline: 1.0322x; 1.0322x over previous
//
#include <hip/hip_runtime.h>
#include <stdint.h>

typedef unsigned short ushort_t;
typedef __bf16 bf16x8 __attribute__((ext_vector_type(8)));
typedef float  f32x4  __attribute__((ext_vector_type(4)));

#define DEV static __device__ __forceinline__

// fp32 -> bf16 round-to-nearest-even
DEV ushort_t f2bf(float f){
  union { float f; unsigned u; } x; x.f = f;
  unsigned u = x.u;
  return (ushort_t)((u + 0x7fffu + ((u >> 16) & 1u)) >> 16);
}

// Boustrophedon map for S=8192 (g=91): involution, maps permuted<->original.
DEV int hmap(int p){
  int r = p / 91;
  int c = p - r * 91;
  return (r & 1) ? (r * 91 + 90 - c) : p;
}

// A-row gather (runtime): 0 identity; 1 = Q permuted order; 2 = compacted dilated KV.
DEV int arow_rt(int r, int gather){
  if (gather == 0) return r;
  if (gather == 1){ int b = r >> 13, p = r & 8191; return b * 8192 + hmap(p); }
  int b = r >> 12, rem = r & 4095, seg = rem >> 6, j = rem & 63;
  return b * 8192 + hmap(seg * 128 + 2 * j);
}

// async global->LDS 16B per lane (LDS dest must be wave-uniform base + lane*16)
DEV void async16(const void* g, void* l){
  __builtin_amdgcn_global_load_lds(
      (const __attribute__((address_space(1))) unsigned*)g,
      (__attribute__((address_space(3))) unsigned*)l, 16, 0, 0);
}

// ---------------- fused prep: cast x + transpose both weights ----------------
// blocks 0..2047: cast x (fp32->bf16, grid-stride over float4)
// blocks 2048..2815: transpose Wqkv [1024][3072] -> WqT [3072][1024]
// blocks 2816..3071: transpose Wout [1024][1024] -> WoT [1024][1024]
__global__ __launch_bounds__(256) void prep_kernel(const float* __restrict__ x,
                                                   const float* __restrict__ Wqkv,
                                                   const float* __restrict__ Wout,
                                                   ushort_t* __restrict__ xb,
                                                   ushort_t* __restrict__ WqT,
                                                   ushort_t* __restrict__ WoT){
  __shared__ ushort_t t[64 * 66];   // pad 66: conflict-free column reads
  int id = blockIdx.x, tid = threadIdx.x;
  if (id < 2048){
    const int n4 = (16384 * 1024) / 4;
    int stride = 2048 * 256;
    for (int i = id * 256 + tid; i < n4; i += stride){
      float4 v = ((const float4*)x)[i];
      ushort4 o;
      o.x = f2bf(v.x); o.y = f2bf(v.y); o.z = f2bf(v.z); o.w = f2bf(v.w);
      ((ushort4*)xb)[i] = o;
    }
    return;
  }
  const float* W; ushort_t* WT; int rows, cols, bx, by;
  if (id < 2816){ int q = id - 2048; W = Wqkv; WT = WqT; rows = 1024; cols = 3072; bx = q % 48; by = q / 48; }
  else          { int q = id - 2816; W = Wout; WT = WoT; rows = 1024; cols = 1024; bx = q % 16; by = q / 16; }
  int c0 = bx * 64, r0 = by * 64;
  int cl = tid & 63, rb = tid >> 6;
  for (int i = 0; i < 16; ++i){
    int r = rb + i * 4;
    t[r * 66 + cl] = f2bf(W[(size_t)(r0 + r) * cols + c0 + cl]);
  }
  __syncthreads();
  int rr = tid & 63, cb = tid >> 6;
  for (int i = 0; i < 16; ++i){
    int cc = cb + i * 4;
    WT[(size_t)(c0 + cc) * rows + r0 + rr] = t[rr * 66 + cc];
  }
}

// ================= 256x256 GEMM body (R4-frozen K-loop) =================
// C[M][N] = A[gather(M)][K] * BT[N][K]^T. BM=BN=256, BK=64, 512 thr (8 waves,
// 2Mx4N, wave tile 128x64). LDS: 4 objects As0/As1/Bs0/Bs1, 128 KiB, 1 blk/CU.
// K-loop frozen: at 898 TF / 36.5% MfmaUtil (R7 measured) this structure is AT
// the documented plain-HIP 2-barrier ceiling (learn_hip m97/m98: ~900TF, 37%).
//   STAGE(t+1 -> other buf); vmcnt(8); barrier; COMPUTE(t); barrier.
// Epilogues (R7 A/B result):
//  * bf16: per-wave LDS re-tile, stride 68 floats (272B: 16B-aligned float4
//    reads, 2-way-free banks) -> ushort4 full-128B-line stores. This fix was
//    -17us on gemm_qkv (93.4->76.5, conflicts halved). KEEP.
//  * fp32: DIRECT stores (R6-measured config). R7's retile on this path was
//    part of an +18us rest-regression; L2 absorbs the half-line RMW anyway
//    (R5 evidence: WRITE halving bought zero time). REVERTED.

#define BARRIER() asm volatile("s_barrier" ::: "memory")
#define VMCNT8()  asm volatile("s_waitcnt vmcnt(8)" ::: "memory")
#define VMCNT0()  asm volatile("s_waitcnt vmcnt(0)" ::: "memory")

#define STAGE_A_TO(DST, T1)                                                    \
  {                                                                            \
    _Pragma("unroll") for (int i = 0; i < 4; ++i)                              \
      async16(&A[asrcR[i] + (size_t)(T1) * 64], &DST[i * 4096 + tid * 8]);     \
  }

#define STAGE_B_TO(DST, T1)                                                    \
  {                                                                            \
    _Pragma("unroll") for (int i = 0; i < 4; ++i)                              \
      async16(&BT[bsrcR[i] + (size_t)(T1) * 64], &DST[i * 4096 + tid * 8]);    \
  }

#define COMPUTE(ABUF, BBUF)                                                    \
  {                                                                            \
    bf16x8 bv[4][2];                                                           \
    _Pragma("unroll") for (int ni = 0; ni < 4; ++ni)                           \
      _Pragma("unroll") for (int kk = 0; kk < 2; ++kk)                         \
        bv[ni][kk] = *(const bf16x8*)&BBUF[(wn * 64 + ni * 16 + md) * 64 + axor[kk]]; \
    _Pragma("unroll") for (int kk = 0; kk < 2; ++kk)                           \
      _Pragma("unroll") for (int mi = 0; mi < 8; ++mi){                        \
        bf16x8 af = *(const bf16x8*)&ABUF[(wm * 128 + mi * 16 + md) * 64 + axor[kk]]; \
        _Pragma("unroll") for (int ni = 0; ni < 4; ++ni)                       \
          acc[mi][ni] = __builtin_amdgcn_mfma_f32_16x16x32_bf16(               \
              af, bv[ni][kk], acc[mi][ni], 0, 0, 0);                           \
      }                                                                        \
  }

#define TILE_STEP(CUR, NXT, TSTAGE)                                            \
  {                                                                            \
    if ((TSTAGE) < NT){                                                        \
      STAGE_A_TO(As##NXT, TSTAGE); STAGE_B_TO(Bs##NXT, TSTAGE);                \
      VMCNT8();                                                                \
    } else { VMCNT0(); }                                                       \
    BARRIER();                                                                 \
    COMPUTE(As##CUR, Bs##CUR);                                                 \
    BARRIER();                                                                 \
  }

template<int OUT_BF16>
DEV void gemm_body(const ushort_t* __restrict__ A, const ushort_t* __restrict__ BT,
                   void* __restrict__ Cout, int N, int K, int gather, int m0, int n0,
                   ushort_t* As0, ushort_t* As1, ushort_t* Bs0, ushort_t* Bs1){
  const int NT = K >> 6;                           // K-tiles (=16, even)
  int tid = threadIdx.x;
  int lane = tid & 63, w = tid >> 6;
  int md = lane & 15, qd = lane >> 4;
  int wm = w >> 2, wn = w & 3;

  // staging: thread covers LDS rows i*64 + (tid>>3), slot tid&7; global chunk
  // g0 = slot ^ (row&7)  ((64*i)&7==0 so g0 is i-independent)
  int rbase = tid >> 3;
  int g0 = ((tid & 7) ^ (rbase & 7)) * 8;          // elems
  size_t asrcR[4], bsrcR[4];
  #pragma unroll
  for (int i = 0; i < 4; ++i){
    asrcR[i] = (size_t)arow_rt(m0 + i * 64 + rbase, gather) * K + g0;
    bsrcR[i] = (size_t)(n0 + i * 64 + rbase) * K + g0;
  }

  // fragment offsets: frag row = (multiple of 8) + md -> row&7 == md&7
  int axor[2] = { (qd ^ (md & 7)) * 8, ((4 + qd) ^ (md & 7)) * 8 };

  f32x4 acc[8][4];
  #pragma unroll
  for (int a = 0; a < 8; ++a)
    #pragma unroll
    for (int b = 0; b < 4; ++b)
      #pragma unroll
      for (int e = 0; e < 4; ++e) acc[a][b][e] = 0.f;

  // prologue: tile 0 into buffers 0 (cold-start latency exposed once)
  STAGE_A_TO(As0, 0);
  STAGE_B_TO(Bs0, 0);
  VMCNT0(); BARRIER();

  for (int t = 0; t < NT; t += 2){
    TILE_STEP(0, 1, t + 1);
    TILE_STEP(1, 0, t + 2);
  }

  // ---- epilogue: 16x16 C/D layout col=lane&15, row=(lane>>4)*4+reg ----
  if (OUT_BF16){
    // Per-wave LDS re-tile (wave-private -> no barrier; LDS free after the
    // final barrier). Stride 68 floats = 272B: float4 reads 16B-aligned,
    // 2-way banks (free, m136). ushort4 x 16 lanes = full 128B line stores.
    float* wbuf = (float*)((w < 4) ? (void*)As0 : (void*)As1) + (w & 3) * 1088;
    int r16 = lane >> 4, c16 = lane & 15;
    #pragma unroll
    for (int mi = 0; mi < 8; ++mi){
      #pragma unroll
      for (int ni = 0; ni < 4; ++ni)
        #pragma unroll
        for (int reg = 0; reg < 4; ++reg)
          wbuf[(qd * 4 + reg) * 68 + ni * 16 + md] = acc[mi][ni][reg];
      // same-wave ds_write -> ds_read ordering is maintained by the LDS unit
      #pragma unroll
      for (int rr = 0; rr < 4; ++rr){
        int row = rr * 4 + r16;
        float4 v = *(const float4*)&wbuf[row * 68 + c16 * 4];
        int grow = m0 + wm * 128 + mi * 16 + row;
        int gcol = n0 + wn * 64 + c16 * 4;
        ushort4 ob;
        ob.x = f2bf(v.x); ob.y = f2bf(v.y); ob.z = f2bf(v.z); ob.w = f2bf(v.w);
        *(ushort4*)&((ushort_t*)Cout)[(size_t)grow * N + gcol] = ob;
      }
    }
  } else {
    // fp32: direct stores (R6-measured configuration)
    #pragma unroll
    for (int mi = 0; mi < 8; ++mi)
      #pragma unroll
      for (int ni = 0; ni < 4; ++ni){
        f32x4 v = acc[mi][ni];
        #pragma unroll
        for (int reg = 0; reg < 4; ++reg){
          int grow = m0 + wm * 128 + mi * 16 + qd * 4 + reg;
          int gcol = n0 + wn * 64 + ni * 16 + md;
          ((float*)Cout)[(size_t)grow * N + gcol] = v[reg];
        }
      }
  }
}

// -------- fused Q + KV projection: 512 blocks, block-routed --------
__global__ __launch_bounds__(512, 2) void gemm_qkv(const ushort_t* __restrict__ xb,
                                                   const ushort_t* __restrict__ WqT,
                                                   ushort_t* __restrict__ Qbuf,
                                                   ushort_t* __restrict__ KVbuf){
  __shared__ __align__(16) ushort_t As0[16384];
  __shared__ __align__(16) ushort_t As1[16384];
  __shared__ __align__(16) ushort_t Bs0[16384];
  __shared__ __align__(16) ushort_t Bs1[16384];
  int id = blockIdx.x;
  const ushort_t* BT; ushort_t* C; int N, gather, m0, n0;
  if (id < 256){
    int o = id;                       // n-major, mtc=64
    m0 = (o & 63) << 8; n0 = (o >> 6) << 8;
    BT = WqT; C = Qbuf; N = 1024; gather = 1;
  } else {
    int o = id - 256;                 // n-major, mtc=32
    m0 = (o & 31) << 8; n0 = (o >> 5) << 8;
    BT = WqT + (size_t)1024 * 1024; C = KVbuf; N = 2048; gather = 2;
  }
  gemm_body<1>(xb, BT, C, N, 1024, gather, m0, n0, As0, As1, Bs0, Bs1);
}

// -------- output projection: fp32 out, identity gather --------
__global__ __launch_bounds__(512, 2) void gemm_out(const ushort_t* __restrict__ aoutb,
                                                   const ushort_t* __restrict__ WoT,
                                                   float* __restrict__ out){
  __shared__ __align__(16) ushort_t As0[16384];
  __shared__ __align__(16) ushort_t As1[16384];
  __shared__ __align__(16) ushort_t Bs0[16384];
  __shared__ __align__(16) ushort_t Bs1[16384];
  int o = blockIdx.x;                 // n-major, mtc=64
  int m0 = (o & 63) << 8, n0 = (o >> 6) << 8;
  gemm_body<0>(aoutb, WoT, out, 1024, 1024, 0, m0, n0, As0, As1, Bs0, Bs1);
}

// ---------------- fused segment attention (R6-verified config) ----------------
// grid (nseg=64, H=16, B=2), block 256 (4 waves).
// Qb:  [B*8192][1024] bf16, rows already in PERMUTED order (gather=1).
// KV:  [B*4096][2048] bf16, compacted dilated rows; cols 0..1023 = K, 1024.. = V.
// uint4 register staging (R7's global_load_lds conversion was the prime
// suspect in an +18us rest-regression; reverted to the R3-R6 measured path).
// Vt stores V transposed with a k-chunk XOR swizzle: plain stride-72 layout
// put all 8 chunk-lanes of the transpose-store in ONE bank (d-stride 144B,
// 144*8 % 128 == 0 -> 8-way conflict x8 elems). Swizzle: k-chunk ^= (d>>3)&7.
__global__ __launch_bounds__(256) void attn_kernel(const ushort_t* __restrict__ Qb,
                                                   const ushort_t* __restrict__ KV,
                                                   ushort_t* __restrict__ aout){
  __shared__ ushort_t Qs[128 * 72];   // reused as P, then as O (wave-private rows)
  __shared__ ushort_t Ks[64 * 72];
  __shared__ ushort_t Vt[64 * 72];    // V transposed: Vt[d][k], k-chunk swizzled
  int tid  = threadIdx.x;
  int lane = tid & 63, w = tid >> 6;
  int qd = lane >> 4, md = lane & 15;
  int seg = blockIdx.x, h = blockIdx.y, b = blockIdx.z;
  int p0 = seg * 128;

  // Q: 128 rows x 64 bf16 (8 chunks of 16B per row), contiguous rows
  for (int it = 0; it < 4; ++it){
    int q = it * 256 + tid;
    int r = q >> 3, ch = q & 7;
    uint4 d = *(const uint4*)&Qb[(size_t)(b * 8192 + p0 + r) * 1024 + h * 64 + ch * 8];
    *(uint4*)&Qs[r * 72 + ch * 8] = d;
  }
  // K: compacted rows seg*64 + r
  for (int it = 0; it < 2; ++it){
    int q = it * 256 + tid;
    int r = q >> 3, ch = q & 7;
    uint4 d = *(const uint4*)&KV[(size_t)(b * 4096 + seg * 64 + r) * 2048 + h * 64 + ch * 8];
    *(uint4*)&Ks[r * 72 + ch * 8] = d;
  }
  // V (cols 1024..2047), stored transposed with swizzled k-chunk:
  // element V[k=r][d=ch*8+e] -> Vt[d*72 + ((r>>3)^ch)*8 + (r&7)]
  for (int it = 0; it < 2; ++it){
    int q = it * 256 + tid;
    int r = q >> 3, ch = q & 7;
    union { uint4 v; ushort_t u[8]; } d;
    d.v = *(const uint4*)&KV[(size_t)(b * 4096 + seg * 64 + r) * 2048 + 1024 + h * 64 + ch * 8];
    int kslot = ((r >> 3) ^ ch) * 8 + (r & 7);
    for (int e = 0; e < 8; ++e) Vt[(ch * 8 + e) * 72 + kslot] = d.u[e];
  }
  __syncthreads();

  // scores: wave w owns q-rows [32w, 32w+32): 2 row-tiles x 4 col-tiles
  f32x4 z = {0.f, 0.f, 0.f, 0.f};
  f32x4 sc[2][4];
  for (int mi = 0; mi < 2; ++mi) for (int ni = 0; ni < 4; ++ni) sc[mi][ni] = z;
  for (int kc = 0; kc < 2; ++kc){
    bf16x8 aq[2], bk[4];
    for (int mi = 0; mi < 2; ++mi)
      aq[mi] = *(const bf16x8*)&Qs[(w * 32 + mi * 16 + md) * 72 + kc * 32 + qd * 8];
    for (int ni = 0; ni < 4; ++ni)
      bk[ni] = *(const bf16x8*)&Ks[(ni * 16 + md) * 72 + kc * 32 + qd * 8];
    for (int mi = 0; mi < 2; ++mi)
      for (int ni = 0; ni < 4; ++ni)
        sc[mi][ni] = __builtin_amdgcn_mfma_f32_16x16x32_bf16(aq[mi], bk[ni], sc[mi][ni], 0, 0, 0);
  }

  // softmax over 64 keys; scale 1/sqrt(64)=0.125. Row r lives in 16 lanes
  // (same quad) x 4 col-tiles -> in-register + shfl_xor(1,2,4,8) reduction.
  const float scale = 0.125f;
  ushort_t* Ps = Qs;  // alias: wave only touches its own 32 rows
  for (int mi = 0; mi < 2; ++mi){
    for (int i = 0; i < 4; ++i){
      float mx = sc[mi][0][i];
      for (int ni = 1; ni < 4; ++ni) mx = fmaxf(mx, sc[mi][ni][i]);
      for (int d = 1; d < 16; d <<= 1) mx = fmaxf(mx, __shfl_xor(mx, d));
      float e[4], sum = 0.f;
      for (int ni = 0; ni < 4; ++ni){ e[ni] = __expf((sc[mi][ni][i] - mx) * scale); sum += e[ni]; }
      for (int d = 1; d < 16; d <<= 1) sum += __shfl_xor(sum, d);
      float inv = 1.0f / sum;
      int r = w * 32 + mi * 16 + qd * 4 + i;
      for (int ni = 0; ni < 4; ++ni)
        Ps[r * 72 + ni * 16 + md] = f2bf(e[ni] * inv);
    }
  }

  // O = P @ V : A = P (rows w*32..+31), B = Vt[d][k] (k-chunk swizzled)
  f32x4 oc[2][4];
  for (int mi = 0; mi < 2; ++mi) for (int ni = 0; ni < 4; ++ni) oc[mi][ni] = z;
  for (int kc = 0; kc < 2; ++kc){
    bf16x8 ap[2], bv[4];
    for (int mi = 0; mi < 2; ++mi)
      ap[mi] = *(const bf16x8*)&Ps[(w * 32 + mi * 16 + md) * 72 + kc * 32 + qd * 8];
    for (int ni = 0; ni < 4; ++ni){
      int dd = ni * 16 + md;
      int vchunk = ((kc * 4 + qd) ^ ((dd >> 3) & 7)) & 7;
      bv[ni] = *(const bf16x8*)&Vt[dd * 72 + vchunk * 8];
    }
    for (int mi = 0; mi < 2; ++mi)
      for (int ni = 0; ni < 4; ++ni)
        oc[mi][ni] = __builtin_amdgcn_mfma_f32_16x16x32_bf16(ap[mi], bv[ni], oc[mi][ni], 0, 0, 0);
  }

  // O back into wave-private LDS rows (overwrites this wave's P), then
  // one barrier and fully-coalesced 16B stores: row s=hmap(p0+r), 128B/row.
  for (int mi = 0; mi < 2; ++mi){
    for (int i = 0; i < 4; ++i){
      int rl = w * 32 + mi * 16 + qd * 4 + i;
      for (int ni = 0; ni < 4; ++ni)
        Ps[rl * 72 + ni * 16 + md] = f2bf(oc[mi][ni][i]);
    }
  }
  __syncthreads();
  for (int it = 0; it < 4; ++it){
    int q = it * 256 + tid;
    int r = q >> 3, ch = q & 7;
    int s = hmap(p0 + r);
    *(uint4*)&aout[(size_t)(b * 8192 + s) * 1024 + h * 64 + ch * 8] =
        *(const uint4*)&Qs[r * 72 + ch * 8];
  }
}

extern "C" void kernel_launch(void* const* d_in, const int* in_sizes, int n_in,
                              void* d_out, int out_size, void* d_ws, size_t ws_size,
                              hipStream_t stream){
  const float* x    = (const float*)d_in[0];   // [2,8192,1024]
  const float* Wqkv = (const float*)d_in[1];   // [1024,3072]
  const float* Wout = (const float*)d_in[2];   // [1024,1024]
  float* out = (float*)d_out;                  // [2,8192,1024]

  // ws layout (bytes): xb 32M | WqT 6M | WoT 2M | Qbuf 32M | KVbuf 32M | aout 32M = 136 MB
  char* ws = (char*)d_ws;
  ushort_t* xb    = (ushort_t*)(ws);
  ushort_t* WqT   = (ushort_t*)(ws + 33554432);
  ushort_t* WoT   = (ushort_t*)(ws + 39845888);
  ushort_t* Qbuf  = (ushort_t*)(ws + 41943040);
  ushort_t* KVbuf = (ushort_t*)(ws + 75497472);
  ushort_t* aoutb = (ushort_t*)(ws + 109051904);

  prep_kernel<<<3072, 256, 0, stream>>>(x, Wqkv, Wout, xb, WqT, WoT);
  gemm_qkv<<<512, 512, 0, stream>>>(xb, WqT, Qbuf, KVbuf);
  attn_kernel<<<dim3(64, 16, 2), 256, 0, stream>>>(Qbuf, KVbuf, aoutb);
  gemm_out<<<256, 512, 0, stream>>>(aoutb, WoT, out);
}